// Round 1
// 712.477 us; speedup vs baseline: 1.0425x; 1.0425x over previous
//
#include <hip/hip_runtime.h>
#include <hip/hip_bf16.h>

// Problem constants
#define B_   8
#define S_   512
#define N_   1024
#define F_   32
#define H_   64
#define G0_  32
#define T_   15          // trailing time steps needed (receptive field of last pos)
#define BT_  (B_ * T_)   // 120
#define C1_  (BT_ * G0_) // 3840 rows of the transposed activation matrices

typedef __bf16 bfx8 __attribute__((ext_vector_type(8)));
typedef __bf16 bfx4 __attribute__((ext_vector_type(4)));
typedef float  f32x4 __attribute__((ext_vector_type(4)));

// async global->LDS, 16B per lane; lds ptr must be wave-uniform (lane*16 implicit)
__device__ __forceinline__ void async16(void* l, const void* g) {
    __builtin_amdgcn_global_load_lds(
        (__attribute__((address_space(1))) const void*)g,
        (__attribute__((address_space(3))) void*)l, 16, 0, 0);
}

// ---------------------------------------------------------------------------
// dis[r] = rsqrt(1 + sum_n adj[r,n])
// ---------------------------------------------------------------------------
__global__ void k_deg(const float* __restrict__ adj, float* __restrict__ dis) {
    int r = blockIdx.x;
    int tid = threadIdx.x;
    const float* row = adj + (size_t)r * N_;
    float p = 0.f;
    for (int n = tid; n < N_; n += 256) p += row[n];
    __shared__ float red[256];
    red[tid] = p;
    __syncthreads();
    for (int s = 128; s > 0; s >>= 1) {
        if (tid < s) red[tid] += red[tid + s];
        __syncthreads();
    }
    if (tid == 0) {
        float deg = red[0] + 1.0f;
        dis[r] = (deg > 0.f) ? rsqrtf(deg) : 0.f;
    }
}

// ---------------------------------------------------------------------------
// AN[m,n] = dis[m]*(adj[m,n] + (m==n))*dis[n], emitted in bf16 (MFMA A-operand)
// ---------------------------------------------------------------------------
__global__ void k_an(const float* __restrict__ adj, const float* __restrict__ dis,
                     __bf16* __restrict__ an) {
    int idx = (blockIdx.x * 256 + threadIdx.x) * 4;   // grid 1024 -> 1M elems
    int m = idx >> 10, n0 = idx & 1023;
    float dm = dis[m];
    float4 a = *(const float4*)&adj[idx];
    float v[4] = {a.x, a.y, a.z, a.w};
    bfx4 o;
#pragma unroll
    for (int j = 0; j < 4; ++j) {
        float vv = v[j] + ((n0 + j) == m ? 1.0f : 0.0f);
        o[j] = (__bf16)(dm * vv * dis[n0 + j]);
    }
    *(bfx4*)&an[idx] = o;
}

// ---------------------------------------------------------------------------
// XW0T[c=bt*32+g][n] = x[b,s(tau),n,:] @ w0[:,g]   (bf16, n contiguous)
// grid (32, 120), block 256
// ---------------------------------------------------------------------------
__global__ void k_xw0(const float* __restrict__ x, const float* __restrict__ w0,
                      __bf16* __restrict__ xw0t) {
    int bt = blockIdx.y, n0 = blockIdx.x * 32, tid = threadIdx.x;
    int b = bt / T_, tau = bt % T_, s = S_ - T_ + tau;
    __shared__ float xs[32][33];    // [n][f], padded
    __shared__ float w0s[32 * 32];  // [f][g]
    const float* xp = x + ((size_t)((b * S_ + s) * N_ + n0)) * F_;
    {
        int r = tid >> 3, c4 = (tid & 7) * 4;
        *(float4*)&xs[r][c4] = *(const float4*)&xp[r * 32 + c4];
        *(float4*)&w0s[tid * 4] = *(const float4*)&w0[tid * 4];
    }
    __syncthreads();
    int g = tid >> 3, nb = (tid & 7) * 4;
    float a0 = 0.f, a1 = 0.f, a2 = 0.f, a3 = 0.f;
#pragma unroll
    for (int f = 0; f < 32; ++f) {
        float wv = w0s[f * 32 + g];
        a0 += xs[nb + 0][f] * wv;
        a1 += xs[nb + 1][f] * wv;
        a2 += xs[nb + 2][f] * wv;
        a3 += xs[nb + 3][f] * wv;
    }
    bfx4 o;
    o[0] = (__bf16)a0; o[1] = (__bf16)a1; o[2] = (__bf16)a2; o[3] = (__bf16)a3;
    *(bfx4*)&xw0t[(size_t)(bt * 32 + g) * N_ + n0 + nb] = o;
}

// ---------------------------------------------------------------------------
// MFMA GEMM: D[m][c] = sum_k A[m][k] * Bm[c][k]   (A: 1024xK row-major bf16,
// Bm: 3840xK row-major bf16, K=1024). Output written TRANSPOSED: C_T[c][m].
// MODE 1: relu(D + bias[c%32]) -> bf16 C_T.   MODE 0: fp32 C_T.
// Tile 128(m) x 128(c), BK=64, 256 threads (4 waves, each 64x64 via 4x4 MFMAs).
// Double-buffered LDS, 2-phase pipeline (stage next tile BEFORE computing
// current; single __syncthreads per tile drains vmcnt -> next buf published,
// current buf protected). XOR-swizzled LDS columns: global source is
// pre-swizzled (global_load_lds dest must stay linear, rule 21), ds_read
// applies the same XOR -> 2-way banked reads instead of 16-way.
// grid (3840/128=30, 1024/128=8)
// ---------------------------------------------------------------------------
template <int MODE>
__global__ __launch_bounds__(256) void k_mm(const __bf16* __restrict__ A,
                                            const __bf16* __restrict__ Bm,
                                            void* __restrict__ Cv,
                                            const float* __restrict__ bias) {
    __shared__ __bf16 As[2][128 * 64];    // 32 KB
    __shared__ __bf16 Bs[2][128 * 64];    // 32 KB
    int tid = threadIdx.x;
    int lane = tid & 63, wv = tid >> 6;
    int rb = blockIdx.y * 128;            // m-block (A rows)
    int cb = blockIdx.x * 128;            // c-block (Bm rows)
    int wr = (wv >> 1) * 64, wc = (wv & 1) * 64;

    f32x4 acc[4][4] = {};

    // staging: per instruction a wave moves 8 rows x 64 bf16 (1 KB), 4 instrs
    // per operand per wave -> 32 rows; 4 waves cover 128 rows.
    int srow = lane >> 3;                         // 0..7 within 8-row chunk
    int scol = ((lane & 7) ^ (srow & 7)) * 8;     // XOR-swizzled source column
    const __bf16* gA = A  + (size_t)(rb + wv * 32 + srow) * 1024 + scol;
    const __bf16* gB = Bm + (size_t)(cb + wv * 32 + srow) * 1024 + scol;

    const int c16 = lane & 15;
    const int qa  = (lane >> 4) * 8;

    // prologue: stage k-step 0 into buffer 0
#pragma unroll
    for (int i = 0; i < 4; ++i) {
        async16(&As[0][(wv * 32 + i * 8) * 64], gA + (size_t)i * 8 * 1024);
        async16(&Bs[0][(wv * 32 + i * 8) * 64], gB + (size_t)i * 8 * 1024);
    }
    __syncthreads();

    int cur = 0;
    for (int t = 0; t < 16; ++t) {
        if (t + 1 < 16) {                 // issue next tile BEFORE compute
            const __bf16* pA = gA + (t + 1) * 64;
            const __bf16* pB = gB + (t + 1) * 64;
#pragma unroll
            for (int i = 0; i < 4; ++i) {
                async16(&As[cur ^ 1][(wv * 32 + i * 8) * 64], pA + (size_t)i * 8 * 1024);
                async16(&Bs[cur ^ 1][(wv * 32 + i * 8) * 64], pB + (size_t)i * 8 * 1024);
            }
        }
#pragma unroll
        for (int kk = 0; kk < 2; ++kk) {
            bfx8 af[4], bfv[4];
#pragma unroll
            for (int r = 0; r < 4; ++r) {
                int row = wr + 16 * r + c16;
                int col = (kk * 64 + qa * 2) ^ ((row & 7) << 4);   // byte offset
                af[r] = *(const bfx8*)((const char*)&As[cur][0] + row * 128 + col);
            }
#pragma unroll
            for (int c = 0; c < 4; ++c) {
                int row = wc + 16 * c + c16;
                int col = (kk * 64 + qa * 2) ^ ((row & 7) << 4);
                bfv[c] = *(const bfx8*)((const char*)&Bs[cur][0] + row * 128 + col);
            }
#pragma unroll
            for (int r = 0; r < 4; ++r)
#pragma unroll
                for (int c = 0; c < 4; ++c)
                    acc[r][c] = __builtin_amdgcn_mfma_f32_16x16x32_bf16(
                        af[r], bfv[c], acc[r][c], 0, 0, 0);
        }
        __syncthreads();                  // drains vmcnt: publishes next buf,
        cur ^= 1;                         // protects current buf from restage
    }

    // Epilogue: lane holds D[m_local = quad*4+reg][c_local = lane&15] per tile.
    int quad = lane >> 4;
    if (MODE == 1) {
        __bf16* C = (__bf16*)Cv;
        float be = bias[c16], bo = bias[c16 + 16];
#pragma unroll
        for (int cj = 0; cj < 4; ++cj) {
            size_t cc = (size_t)(cb + wc + 16 * cj + c16);
            float bg = (cj & 1) ? bo : be;
#pragma unroll
            for (int r = 0; r < 4; ++r) {
                int m4 = rb + wr + 16 * r + quad * 4;
                f32x4 v = acc[r][cj];
                bfx4 o;
#pragma unroll
                for (int j = 0; j < 4; ++j) o[j] = (__bf16)fmaxf(v[j] + bg, 0.f);
                *(bfx4*)&C[cc * 1024 + m4] = o;
            }
        }
    } else {
        float* C = (float*)Cv;
#pragma unroll
        for (int cj = 0; cj < 4; ++cj) {
            size_t cc = (size_t)(cb + wc + 16 * cj + c16);
#pragma unroll
            for (int r = 0; r < 4; ++r) {
                int m4 = rb + wr + 16 * r + quad * 4;
                *(f32x4*)&C[cc * 1024 + m4] = acc[r][cj];
            }
        }
    }
}

// ---------------------------------------------------------------------------
// Partial h2-mean: block (bt, q) computes, for its 256-wide m-stripe,
// partial[bt][q][h] = sum_{m in stripe} relu( sum_g AGT[bt*32+g][m]*w1[g,h] + b1[h] )
// AGT is fp32 [3840][1024]. grid 480 (=120*4), block 256. 1/N applied by k_head.
// Thread owns h (w1 column in 32 registers) + a 64-wide m sub-stripe; AG values
// are wave-uniform float4 loads (scalarizable) — no LDS in the hot loop.
// ---------------------------------------------------------------------------
__global__ __launch_bounds__(256) void k_h2mean(const float* __restrict__ AGT,
                                                const float* __restrict__ w1,
                                                const float* __restrict__ b1,
                                                float* __restrict__ spatialP) {
    int blk = blockIdx.x;
    int bt = blk >> 2, q = blk & 3;
    int tid = threadIdx.x;
    int h = tid & 63, sub = tid >> 6;
    float w1r[32];
#pragma unroll
    for (int g = 0; g < 32; ++g) w1r[g] = w1[g * 64 + h];
    float bh = b1[h];
    float acc = 0.f;
    const float* base = AGT + (size_t)(bt * 32) * 1024 + q * 256 + sub * 64;
    for (int mq = 0; mq < 16; ++mq) {
        float v0 = bh, v1 = bh, v2 = bh, v3 = bh;
#pragma unroll
        for (int g = 0; g < 32; ++g) {
            float4 a = *(const float4*)(base + (size_t)g * 1024 + mq * 4);
            v0 += a.x * w1r[g];
            v1 += a.y * w1r[g];
            v2 += a.z * w1r[g];
            v3 += a.w * w1r[g];
        }
        acc += fmaxf(v0, 0.f) + fmaxf(v1, 0.f) + fmaxf(v2, 0.f) + fmaxf(v3, 0.f);
    }
    __shared__ float red[4][64];
    red[sub][h] = acc;
    __syncthreads();
    if (tid < 64) {
        spatialP[(size_t)blk * 64 + tid] =
            red[0][tid] + red[1][tid] + red[2][tid] + red[3][tid];
    }
}

// ---------------------------------------------------------------------------
// temporal conv stack (needed positions only) + fusion + prediction MLP
// grid 8 (one block per batch), 256 threads. Conv weights staged to LDS in
// [k][i][o] layout, 65-float row stride (the natural [o][i][k] read has
// stride 192 == 0 mod 32 -> 64-way bank conflict).
// Reads spatialP partials (4 per (bt,h)) and applies the 1/N scaling.
// ---------------------------------------------------------------------------
__global__ __launch_bounds__(256) void k_head(const float* __restrict__ spatialP,
                       const float* __restrict__ cw0, const float* __restrict__ cb0,
                       const float* __restrict__ cw1, const float* __restrict__ cb1,
                       const float* __restrict__ cw2, const float* __restrict__ cb2,
                       const float* __restrict__ fw,  const float* __restrict__ fb,
                       const float* __restrict__ pw1, const float* __restrict__ pb1,
                       const float* __restrict__ pw2, const float* __restrict__ pb2,
                       float* __restrict__ out) {
    int b = blockIdx.x, tid = threadIdx.x;
    int o = tid & 63, ti = tid >> 6;
    __shared__ float wbuf[3 * 64 * 65];            // [k][i][o], padded (48.75 KB)
    __shared__ float sp[15][64], c0s[15][64], c1s[15][64];
    __shared__ float lastv[64], fusedv[64], p1s[32];

    for (int j = tid; j < 15 * 64; j += 256) {
        int t = j >> 6, i = j & 63;
        const float* P = spatialP + ((size_t)(b * 15 + t) * 4) * 64 + i;
        ((float*)sp)[j] = (P[0] + P[64] + P[128] + P[192]) * (1.0f / N_);
    }
    for (int j = tid; j < 12288; j += 256) {       // cw0 -> [k][i][o]
        int oo = j / 192, r = j % 192, ii = r / 3, kk = r % 3;
        wbuf[kk * 4160 + ii * 65 + oo] = cw0[j];
    }
    __syncthreads();
    // conv0 (dil 1) at tau = 2,4,...,14 (same FMA order as verified scalar ver.)
    for (int t4 = ti; t4 < 7; t4 += 4) {
        int t = 2 + 2 * t4;
        float v = cb0[o];
#pragma unroll
        for (int k = 0; k < 3; ++k) {
            const float* in = sp[t - 2 + k];
            const float* wk = &wbuf[k * 4160];
#pragma unroll
            for (int i = 0; i < 64; ++i) v += wk[i * 65 + o] * in[i];
        }
        c0s[t][o] = fmaxf(v, 0.f);
    }
    __syncthreads();
    for (int j = tid; j < 12288; j += 256) {       // cw1 -> [k][i][o]
        int oo = j / 192, r = j % 192, ii = r / 3, kk = r % 3;
        wbuf[kk * 4160 + ii * 65 + oo] = cw1[j];
    }
    __syncthreads();
    // conv1 (dil 2) at tau = 6,10,14
    if (ti < 3) {
        int t = 6 + 4 * ti;
        float v = cb1[o];
#pragma unroll
        for (int k = 0; k < 3; ++k) {
            const float* in = c0s[t - (2 - k) * 2];
            const float* wk = &wbuf[k * 4160];
#pragma unroll
            for (int i = 0; i < 64; ++i) v += wk[i * 65 + o] * in[i];
        }
        c1s[t][o] = fmaxf(v, 0.f);
    }
    __syncthreads();
    for (int j = tid; j < 12288; j += 256) {       // cw2 -> [k][i][o]
        int oo = j / 192, r = j % 192, ii = r / 3, kk = r % 3;
        wbuf[kk * 4160 + ii * 65 + oo] = cw2[j];
    }
    __syncthreads();
    // conv2 (dil 4) at tau = 14
    if (ti == 0) {
        float v = cb2[o];
#pragma unroll
        for (int k = 0; k < 3; ++k) {
            const float* in = c1s[14 - (2 - k) * 4];
            const float* wk = &wbuf[k * 4160];
#pragma unroll
            for (int i = 0; i < 64; ++i) v += wk[i * 65 + o] * in[i];
        }
        lastv[o] = fmaxf(v, 0.f);
    }
    __syncthreads();
    if (ti == 0) {                                  // fusion
        float v = fb[o];
#pragma unroll
        for (int i = 0; i < 64; ++i) v += lastv[i] * fw[i * 64 + o];
        fusedv[o] = fmaxf(v, 0.f);
    }
    __syncthreads();
    if (tid < 32) {                                 // pred layer 1
        float v = pb1[tid];
#pragma unroll
        for (int i = 0; i < 64; ++i) v += fusedv[i] * pw1[i * 32 + tid];
        p1s[tid] = fmaxf(v, 0.f);
    }
    __syncthreads();
    if (tid == 0) {                                 // pred layer 2
        float v = pb2[0];
#pragma unroll
        for (int i = 0; i < 32; ++i) v += p1s[i] * pw2[i];
        out[b] = v;
    }
}

// ---------------------------------------------------------------------------
extern "C" void kernel_launch(void* const* d_in, const int* in_sizes, int n_in,
                              void* d_out, int out_size, void* d_ws, size_t ws_size,
                              hipStream_t stream) {
    (void)in_sizes; (void)n_in; (void)out_size; (void)ws_size;
    const float* x   = (const float*)d_in[0];
    const float* adj = (const float*)d_in[1];
    const float* w0  = (const float*)d_in[2];
    const float* b0  = (const float*)d_in[3];
    const float* w1  = (const float*)d_in[4];
    const float* b1  = (const float*)d_in[5];
    const float* cw0 = (const float*)d_in[6];
    const float* cb0 = (const float*)d_in[7];
    const float* cw1 = (const float*)d_in[8];
    const float* cb1 = (const float*)d_in[9];
    const float* cw2 = (const float*)d_in[10];
    const float* cb2 = (const float*)d_in[11];
    const float* fw  = (const float*)d_in[12];
    const float* fb  = (const float*)d_in[13];
    const float* pw1 = (const float*)d_in[14];
    const float* pb1 = (const float*)d_in[15];
    const float* pw2 = (const float*)d_in[16];
    const float* pb2 = (const float*)d_in[17];
    float* outp = (float*)d_out;

    // Workspace layout (bytes, all 16B-aligned)
    char* w = (char*)d_ws;
    float*  dis      = (float*)(w);                       //   4 KB
    __bf16* an       = (__bf16*)(w + 4096);               //   2 MB
    __bf16* xw0t     = (__bf16*)(w + 4096 + 2097152);     // 7.5 MB (3840x1024 bf16)
    __bf16* h1t      = (__bf16*)(w + 4096 + 2097152 + 7864320);
    float*  agt      = (float*) (w + 4096 + 2097152 + 2 * 7864320);   // 15 MB fp32
    float*  spatialP = (float*) (w + 4096 + 2097152 + 2 * 7864320 + 15728640); // 120 KB

    k_deg<<<N_, 256, 0, stream>>>(adj, dis);
    k_an<<<(N_ * N_) / 1024, 256, 0, stream>>>(adj, dis, an);
    k_xw0<<<dim3(N_ / 32, BT_), 256, 0, stream>>>(x, w0, xw0t);
    k_mm<1><<<dim3(C1_ / 128, N_ / 128), 256, 0, stream>>>(an, xw0t, (void*)h1t, b0);
    k_mm<0><<<dim3(C1_ / 128, N_ / 128), 256, 0, stream>>>(an, h1t, (void*)agt, nullptr);
    k_h2mean<<<BT_ * 4, 256, 0, stream>>>(agt, w1, b1, spatialP);
    k_head<<<B_, 256, 0, stream>>>(spatialP, cw0, cb0, cw1, cb1, cw2, cb2,
                                   fw, fb, pw1, pb1, pw2, pb2, outp);
}

// Round 2
// 699.722 us; speedup vs baseline: 1.0615x; 1.0182x over previous
//
#include <hip/hip_runtime.h>
#include <hip/hip_bf16.h>

// Problem constants
#define B_   8
#define S_   512
#define N_   1024
#define F_   32
#define H_   64
#define G0_  32
#define T_   15          // trailing time steps needed (receptive field of last pos)
#define BT_  (B_ * T_)   // 120
#define C1_  (BT_ * G0_) // 3840 rows of the transposed activation matrices

typedef __bf16 bfx8 __attribute__((ext_vector_type(8)));
typedef __bf16 bfx4 __attribute__((ext_vector_type(4)));
typedef float  f32x4 __attribute__((ext_vector_type(4)));

// async global->LDS, 16B per lane; lds ptr must be wave-uniform (lane*16 implicit)
__device__ __forceinline__ void async16(void* l, const void* g) {
    __builtin_amdgcn_global_load_lds(
        (__attribute__((address_space(1))) const void*)g,
        (__attribute__((address_space(3))) void*)l, 16, 0, 0);
}

// ---------------------------------------------------------------------------
// dis[r] = rsqrt(1 + sum_n adj[r,n])
// ---------------------------------------------------------------------------
__global__ void k_deg(const float* __restrict__ adj, float* __restrict__ dis) {
    int r = blockIdx.x;
    int tid = threadIdx.x;
    const float* row = adj + (size_t)r * N_;
    float p = 0.f;
    for (int n = tid; n < N_; n += 256) p += row[n];
    __shared__ float red[256];
    red[tid] = p;
    __syncthreads();
    for (int s = 128; s > 0; s >>= 1) {
        if (tid < s) red[tid] += red[tid + s];
        __syncthreads();
    }
    if (tid == 0) {
        float deg = red[0] + 1.0f;
        dis[r] = (deg > 0.f) ? rsqrtf(deg) : 0.f;
    }
}

// ---------------------------------------------------------------------------
// AN[m,n] = dis[m]*(adj[m,n] + (m==n))*dis[n], emitted in bf16 (MFMA A-operand)
// ---------------------------------------------------------------------------
__global__ void k_an(const float* __restrict__ adj, const float* __restrict__ dis,
                     __bf16* __restrict__ an) {
    int idx = (blockIdx.x * 256 + threadIdx.x) * 4;   // grid 1024 -> 1M elems
    int m = idx >> 10, n0 = idx & 1023;
    float dm = dis[m];
    float4 a = *(const float4*)&adj[idx];
    float v[4] = {a.x, a.y, a.z, a.w};
    bfx4 o;
#pragma unroll
    for (int j = 0; j < 4; ++j) {
        float vv = v[j] + ((n0 + j) == m ? 1.0f : 0.0f);
        o[j] = (__bf16)(dm * vv * dis[n0 + j]);
    }
    *(bfx4*)&an[idx] = o;
}

// ---------------------------------------------------------------------------
// Conv-weight pre-transpose: [o][i][k] -> [k][i][o] with 65-float row pad.
// One layer = 3*64*65 = 12480 floats; 3 layers concatenated. grid 147.
// ---------------------------------------------------------------------------
__global__ void k_wprep(const float* __restrict__ cw0, const float* __restrict__ cw1,
                        const float* __restrict__ cw2, float* __restrict__ wp) {
    int idx = blockIdx.x * 256 + threadIdx.x;
    if (idx >= 3 * 12480) return;
    int layer = idx / 12480, r = idx % 12480;
    int kk = r / 4160, r2 = r % 4160, ii = r2 / 65, oo = r2 % 65;
    const float* src = (layer == 0) ? cw0 : ((layer == 1) ? cw1 : cw2);
    wp[idx] = (oo < 64) ? src[oo * 192 + ii * 3 + kk] : 0.f;
}

// ---------------------------------------------------------------------------
// XW0T[c=bt*32+g][n] = x[b,s(tau),n,:] @ w0[:,g]   (bf16, n contiguous)
// grid (32, 120), block 256
// ---------------------------------------------------------------------------
__global__ void k_xw0(const float* __restrict__ x, const float* __restrict__ w0,
                      __bf16* __restrict__ xw0t) {
    int bt = blockIdx.y, n0 = blockIdx.x * 32, tid = threadIdx.x;
    int b = bt / T_, tau = bt % T_, s = S_ - T_ + tau;
    __shared__ float xs[32][33];    // [n][f], padded
    __shared__ float w0s[32 * 32];  // [f][g]
    const float* xp = x + ((size_t)((b * S_ + s) * N_ + n0)) * F_;
    {
        int r = tid >> 3, c4 = (tid & 7) * 4;
        *(float4*)&xs[r][c4] = *(const float4*)&xp[r * 32 + c4];
        *(float4*)&w0s[tid * 4] = *(const float4*)&w0[tid * 4];
    }
    __syncthreads();
    int g = tid >> 3, nb = (tid & 7) * 4;
    float a0 = 0.f, a1 = 0.f, a2 = 0.f, a3 = 0.f;
#pragma unroll
    for (int f = 0; f < 32; ++f) {
        float wv = w0s[f * 32 + g];
        a0 += xs[nb + 0][f] * wv;
        a1 += xs[nb + 1][f] * wv;
        a2 += xs[nb + 2][f] * wv;
        a3 += xs[nb + 3][f] * wv;
    }
    bfx4 o;
    o[0] = (__bf16)a0; o[1] = (__bf16)a1; o[2] = (__bf16)a2; o[3] = (__bf16)a3;
    *(bfx4*)&xw0t[(size_t)(bt * 32 + g) * N_ + n0 + nb] = o;
}

// ---------------------------------------------------------------------------
// MFMA GEMM: D[m][c] = sum_k A[m][k] * Bm[c][k]   (A: 1024xK row-major bf16,
// Bm: 3840xK row-major bf16, K=1024). Output written TRANSPOSED: C_T[c][m].
// MODE 1: relu(D + bias[c%32]) -> bf16 C_T.   MODE 0: fp32 C_T.
// Tile 128(m) x 128(c), BK=64, 512 threads = 8 waves (2 waves/SIMD for TLP:
// one wave's MFMA hides the other's barrier vmcnt-drain). Each wave owns a
// 64(m) x 32(c) sub-tile (4x2 MFMA frags). Double-buffered LDS, stage-next-
// before-compute, one __syncthreads per K-step. XOR-swizzled LDS columns
// (pre-swizzled global source, same XOR on ds_read -> 2-way banked = free).
// grid (3840/128=30, 1024/128=8)
// ---------------------------------------------------------------------------
template <int MODE>
__global__ __launch_bounds__(512) void k_mm(const __bf16* __restrict__ A,
                                            const __bf16* __restrict__ Bm,
                                            void* __restrict__ Cv,
                                            const float* __restrict__ bias) {
    __shared__ __bf16 As[2][128 * 64];    // 32 KB
    __shared__ __bf16 Bs[2][128 * 64];    // 32 KB
    int tid = threadIdx.x;
    int lane = tid & 63, wv = tid >> 6;   // wv 0..7
    int rb = blockIdx.y * 128;            // m-block (A rows)
    int cb = blockIdx.x * 128;            // c-block (Bm rows)
    int wr = (wv >> 2) * 64;              // 0 / 64      (m sub-block)
    int wc = (wv & 3) * 32;               // 0/32/64/96  (c sub-block)

    f32x4 acc[4][2] = {};

    // staging: per async16 a wave moves 8 rows x 64 bf16 (1 KB); 2 per operand
    // per wave -> 16 rows; 8 waves cover 128 rows.
    int srow = lane >> 3;                         // 0..7 within 8-row chunk
    int scol = ((lane & 7) ^ (srow & 7)) * 8;     // XOR-swizzled source column
    const __bf16* gA = A  + (size_t)(rb + wv * 16 + srow) * 1024 + scol;
    const __bf16* gB = Bm + (size_t)(cb + wv * 16 + srow) * 1024 + scol;

    const int c16 = lane & 15;
    const int qa  = (lane >> 4) * 8;

    // prologue: stage k-step 0 into buffer 0
#pragma unroll
    for (int i = 0; i < 2; ++i) {
        async16(&As[0][(wv * 16 + i * 8) * 64], gA + (size_t)i * 8 * 1024);
        async16(&Bs[0][(wv * 16 + i * 8) * 64], gB + (size_t)i * 8 * 1024);
    }
    __syncthreads();

    int cur = 0;
    for (int t = 0; t < 16; ++t) {
        if (t + 1 < 16) {                 // issue next tile BEFORE compute
            const __bf16* pA = gA + (t + 1) * 64;
            const __bf16* pB = gB + (t + 1) * 64;
#pragma unroll
            for (int i = 0; i < 2; ++i) {
                async16(&As[cur ^ 1][(wv * 16 + i * 8) * 64], pA + (size_t)i * 8 * 1024);
                async16(&Bs[cur ^ 1][(wv * 16 + i * 8) * 64], pB + (size_t)i * 8 * 1024);
            }
        }
#pragma unroll
        for (int kk = 0; kk < 2; ++kk) {
            bfx8 af[4], bfv[2];
#pragma unroll
            for (int r = 0; r < 4; ++r) {
                int row = wr + 16 * r + c16;
                int col = (kk * 64 + qa * 2) ^ ((row & 7) << 4);   // byte offset
                af[r] = *(const bfx8*)((const char*)&As[cur][0] + row * 128 + col);
            }
#pragma unroll
            for (int c = 0; c < 2; ++c) {
                int row = wc + 16 * c + c16;
                int col = (kk * 64 + qa * 2) ^ ((row & 7) << 4);
                bfv[c] = *(const bfx8*)((const char*)&Bs[cur][0] + row * 128 + col);
            }
#pragma unroll
            for (int r = 0; r < 4; ++r)
#pragma unroll
                for (int c = 0; c < 2; ++c)
                    acc[r][c] = __builtin_amdgcn_mfma_f32_16x16x32_bf16(
                        af[r], bfv[c], acc[r][c], 0, 0, 0);
        }
        __syncthreads();                  // drains vmcnt: publishes next buf,
        cur ^= 1;                         // protects current buf from restage
    }

    // Epilogue: lane holds D[m_local = quad*4+reg][c_local = lane&15] per tile.
    // (wc multiple of 32 -> bias index (wc+16cj+c16)&31 == c16 + 16*(cj&1).)
    int quad = lane >> 4;
    if (MODE == 1) {
        __bf16* C = (__bf16*)Cv;
        float be = bias[c16], bo = bias[c16 + 16];
#pragma unroll
        for (int cj = 0; cj < 2; ++cj) {
            size_t cc = (size_t)(cb + wc + 16 * cj + c16);
            float bg = (cj & 1) ? bo : be;
#pragma unroll
            for (int r = 0; r < 4; ++r) {
                int m4 = rb + wr + 16 * r + quad * 4;
                f32x4 v = acc[r][cj];
                bfx4 o;
#pragma unroll
                for (int j = 0; j < 4; ++j) o[j] = (__bf16)fmaxf(v[j] + bg, 0.f);
                *(bfx4*)&C[cc * 1024 + m4] = o;
            }
        }
    } else {
        float* C = (float*)Cv;
#pragma unroll
        for (int cj = 0; cj < 2; ++cj) {
            size_t cc = (size_t)(cb + wc + 16 * cj + c16);
#pragma unroll
            for (int r = 0; r < 4; ++r) {
                int m4 = rb + wr + 16 * r + quad * 4;
                *(f32x4*)&C[cc * 1024 + m4] = acc[r][cj];
            }
        }
    }
}

// ---------------------------------------------------------------------------
// Partial h2-mean: block (bt, q) computes, for its 256-wide m-stripe,
// partial[bt][q][h] = sum_{m in stripe} relu( sum_g AGT[bt*32+g][m]*w1[g,h] + b1[h] )
// AGT is fp32 [3840][1024]. grid 480 (=120*4), block 256. 1/N applied by k_head.
// ---------------------------------------------------------------------------
__global__ __launch_bounds__(256) void k_h2mean(const float* __restrict__ AGT,
                                                const float* __restrict__ w1,
                                                const float* __restrict__ b1,
                                                float* __restrict__ spatialP) {
    int blk = blockIdx.x;
    int bt = blk >> 2, q = blk & 3;
    int tid = threadIdx.x;
    int h = tid & 63, sub = tid >> 6;
    float w1r[32];
#pragma unroll
    for (int g = 0; g < 32; ++g) w1r[g] = w1[g * 64 + h];
    float bh = b1[h];
    float acc = 0.f;
    const float* base = AGT + (size_t)(bt * 32) * 1024 + q * 256 + sub * 64;
    for (int mq = 0; mq < 16; ++mq) {
        float v0 = bh, v1 = bh, v2 = bh, v3 = bh;
#pragma unroll
        for (int g = 0; g < 32; ++g) {
            float4 a = *(const float4*)(base + (size_t)g * 1024 + mq * 4);
            v0 += a.x * w1r[g];
            v1 += a.y * w1r[g];
            v2 += a.z * w1r[g];
            v3 += a.w * w1r[g];
        }
        acc += fmaxf(v0, 0.f) + fmaxf(v1, 0.f) + fmaxf(v2, 0.f) + fmaxf(v3, 0.f);
    }
    __shared__ float red[4][64];
    red[sub][h] = acc;
    __syncthreads();
    if (tid < 64) {
        spatialP[(size_t)blk * 64 + tid] =
            red[0][tid] + red[1][tid] + red[2][tid] + red[3][tid];
    }
}

// ---------------------------------------------------------------------------
// temporal conv stack (needed positions only) + fusion + prediction MLP
// grid 8 (one block per batch), 256 threads. Conv weights come pre-transposed
// from k_wprep ([k][i][o], 65-float padded rows) -> staging is a plain
// float4 copy (the natural [o][i][k] read has stride 192 == 0 mod 32 ->
// 64-way bank conflict; the 65 pad gives conflict-free reads).
// Reads spatialP partials (4 per (bt,h)) and applies the 1/N scaling.
// ---------------------------------------------------------------------------
__global__ __launch_bounds__(256) void k_head(const float* __restrict__ spatialP,
                       const float* __restrict__ wp,
                       const float* __restrict__ cb0, const float* __restrict__ cb1,
                       const float* __restrict__ cb2,
                       const float* __restrict__ fw,  const float* __restrict__ fb,
                       const float* __restrict__ pw1, const float* __restrict__ pb1,
                       const float* __restrict__ pw2, const float* __restrict__ pb2,
                       float* __restrict__ out) {
    int b = blockIdx.x, tid = threadIdx.x;
    int o = tid & 63, ti = tid >> 6;
    __shared__ float wbuf[3 * 64 * 65];            // [k][i][o], padded (48.75 KB)
    __shared__ float sp[15][64], c0s[15][64], c1s[15][64];
    __shared__ float lastv[64], fusedv[64], p1s[32];

    for (int j = tid; j < 15 * 64; j += 256) {
        int t = j >> 6, i = j & 63;
        const float* P = spatialP + ((size_t)(b * 15 + t) * 4) * 64 + i;
        ((float*)sp)[j] = (P[0] + P[64] + P[128] + P[192]) * (1.0f / N_);
    }
    for (int j4 = tid; j4 < 3120; j4 += 256)       // layer-0 weights
        *(float4*)&wbuf[j4 * 4] = *(const float4*)&wp[j4 * 4];
    __syncthreads();
    // conv0 (dil 1) at tau = 2,4,...,14 (same FMA order as verified scalar ver.)
    for (int t4 = ti; t4 < 7; t4 += 4) {
        int t = 2 + 2 * t4;
        float v = cb0[o];
#pragma unroll
        for (int k = 0; k < 3; ++k) {
            const float* in = sp[t - 2 + k];
            const float* wk = &wbuf[k * 4160];
#pragma unroll
            for (int i = 0; i < 64; ++i) v += wk[i * 65 + o] * in[i];
        }
        c0s[t][o] = fmaxf(v, 0.f);
    }
    __syncthreads();
    for (int j4 = tid; j4 < 3120; j4 += 256)       // layer-1 weights
        *(float4*)&wbuf[j4 * 4] = *(const float4*)&wp[12480 + j4 * 4];
    __syncthreads();
    // conv1 (dil 2) at tau = 6,10,14
    if (ti < 3) {
        int t = 6 + 4 * ti;
        float v = cb1[o];
#pragma unroll
        for (int k = 0; k < 3; ++k) {
            const float* in = c0s[t - (2 - k) * 2];
            const float* wk = &wbuf[k * 4160];
#pragma unroll
            for (int i = 0; i < 64; ++i) v += wk[i * 65 + o] * in[i];
        }
        c1s[t][o] = fmaxf(v, 0.f);
    }
    __syncthreads();
    for (int j4 = tid; j4 < 3120; j4 += 256)       // layer-2 weights
        *(float4*)&wbuf[j4 * 4] = *(const float4*)&wp[24960 + j4 * 4];
    __syncthreads();
    // conv2 (dil 4) at tau = 14
    if (ti == 0) {
        float v = cb2[o];
#pragma unroll
        for (int k = 0; k < 3; ++k) {
            const float* in = c1s[14 - (2 - k) * 4];
            const float* wk = &wbuf[k * 4160];
#pragma unroll
            for (int i = 0; i < 64; ++i) v += wk[i * 65 + o] * in[i];
        }
        lastv[o] = fmaxf(v, 0.f);
    }
    __syncthreads();
    if (ti == 0) {                                  // fusion
        float v = fb[o];
#pragma unroll
        for (int i = 0; i < 64; ++i) v += lastv[i] * fw[i * 64 + o];
        fusedv[o] = fmaxf(v, 0.f);
    }
    __syncthreads();
    if (tid < 32) {                                 // pred layer 1
        float v = pb1[tid];
#pragma unroll
        for (int i = 0; i < 64; ++i) v += fusedv[i] * pw1[i * 32 + tid];
        p1s[tid] = fmaxf(v, 0.f);
    }
    __syncthreads();
    if (tid == 0) {                                 // pred layer 2
        float v = pb2[0];
#pragma unroll
        for (int i = 0; i < 32; ++i) v += p1s[i] * pw2[i];
        out[b] = v;
    }
}

// ---------------------------------------------------------------------------
extern "C" void kernel_launch(void* const* d_in, const int* in_sizes, int n_in,
                              void* d_out, int out_size, void* d_ws, size_t ws_size,
                              hipStream_t stream) {
    (void)in_sizes; (void)n_in; (void)out_size; (void)ws_size;
    const float* x   = (const float*)d_in[0];
    const float* adj = (const float*)d_in[1];
    const float* w0  = (const float*)d_in[2];
    const float* b0  = (const float*)d_in[3];
    const float* w1  = (const float*)d_in[4];
    const float* b1  = (const float*)d_in[5];
    const float* cw0 = (const float*)d_in[6];
    const float* cb0 = (const float*)d_in[7];
    const float* cw1 = (const float*)d_in[8];
    const float* cb1 = (const float*)d_in[9];
    const float* cw2 = (const float*)d_in[10];
    const float* cb2 = (const float*)d_in[11];
    const float* fw  = (const float*)d_in[12];
    const float* fb  = (const float*)d_in[13];
    const float* pw1 = (const float*)d_in[14];
    const float* pb1 = (const float*)d_in[15];
    const float* pw2 = (const float*)d_in[16];
    const float* pb2 = (const float*)d_in[17];
    float* outp = (float*)d_out;

    // Workspace layout (bytes, all 16B-aligned)
    char* w = (char*)d_ws;
    float*  dis      = (float*)(w);                       //   4 KB
    __bf16* an       = (__bf16*)(w + 4096);               //   2 MB
    __bf16* xw0t     = (__bf16*)(w + 4096 + 2097152);     // 7.5 MB (3840x1024 bf16)
    __bf16* h1t      = (__bf16*)(w + 4096 + 2097152 + 7864320);
    float*  agt      = (float*) (w + 4096 + 2097152 + 2 * 7864320);   // 15 MB fp32
    float*  spatialP = (float*) (w + 4096 + 2097152 + 2 * 7864320 + 15728640); // 120 KB
    float*  wp       = (float*) (w + 4096 + 2097152 + 2 * 7864320 + 15728640 + 122880);

    k_deg<<<N_, 256, 0, stream>>>(adj, dis);
    k_an<<<(N_ * N_) / 1024, 256, 0, stream>>>(adj, dis, an);
    k_wprep<<<147, 256, 0, stream>>>(cw0, cw1, cw2, wp);
    k_xw0<<<dim3(N_ / 32, BT_), 256, 0, stream>>>(x, w0, xw0t);
    k_mm<1><<<dim3(C1_ / 128, N_ / 128), 512, 0, stream>>>(an, xw0t, (void*)h1t, b0);
    k_mm<0><<<dim3(C1_ / 128, N_ / 128), 512, 0, stream>>>(an, h1t, (void*)agt, nullptr);
    k_h2mean<<<BT_ * 4, 256, 0, stream>>>(agt, w1, b1, spatialP);
    k_head<<<B_, 256, 0, stream>>>(spatialP, wp, cb0, cb1, cb2,
                                   fw, fb, pw1, pb1, pw2, pb2, outp);
}